// Round 6
// baseline (99.027 us; speedup 1.0000x reference)
//
#include <hip/hip_runtime.h>

#define E  1024
#define H  64
#define BB 8
#define TT 2048

typedef __attribute__((ext_vector_type(8))) short bf16x8;
typedef __attribute__((ext_vector_type(4))) float f32x4;
typedef __attribute__((ext_vector_type(8))) short short8;
typedef __attribute__((ext_vector_type(4))) short short4v;

__device__ __forceinline__ short f2bf(float f) {
    union { float f; unsigned u; } v; v.f = f;
    unsigned r = v.u + 0x7FFFu + ((v.u >> 16) & 1u);   // RNE
    return (short)(r >> 16);
}

// ---- pack W into B-fragment layout for mfma_f32_16x16x32_bf16 ----
__global__ __launch_bounds__(256)
void pack_w(const float* __restrict__ Wq, const float* __restrict__ Wk,
            const float* __restrict__ Wv, short* __restrict__ Wb)
{
    const int t  = blockIdx.x * 256 + threadIdx.x;   // 24576 total
    const int l  = t & 63;
    const int f  = (t >> 6) % 12;
    const int kc = t / 768;                          // kchunk 0..31
    const float* W = (f < 4) ? Wq : ((f < 8) ? Wk : Wv);
    const int e0 = kc * 32 + ((l >> 4) << 3);
    const int n  = ((f & 3) << 4) + (l & 15);
    short8 o;
    #pragma unroll
    for (int j = 0; j < 8; ++j) o[j] = f2bf(W[(e0 + j) * 64 + n]);
    *(short8*)&Wb[(size_t)t * 8] = o;
}

// ---- split-K MFMA projection; writes q,k row-major and V TRANSPOSED ----
__global__ __launch_bounds__(256)
void proj_mfma(const float* __restrict__ x, const short* __restrict__ Wb,
               short* __restrict__ q, short* __restrict__ k, short* __restrict__ vt)
{
    __shared__ float part[2][12][64][4];   // 24 KB: kh=1 partials
    const int t   = threadIdx.x;
    const int l   = t & 63;
    const int wid = t >> 6;
    const int wm  = wid & 1, kh = wid >> 1;
    const long row0 = (long)blockIdx.x * 32 + wm * 16;
    const int l15 = l & 15, g = l >> 4;

    f32x4 acc[12];
    #pragma unroll
    for (int f = 0; f < 12; ++f) acc[f] = (f32x4){0.f, 0.f, 0.f, 0.f};

    const float* xp = x + (row0 + l15) * E + kh * 512 + g * 8;
    const short* wp = Wb + (size_t)(kh * 16) * 12 * 512 + (size_t)l * 8;

    for (int kc = 0; kc < 16; ++kc) {
        float4 a0 = *(const float4*)(xp);
        float4 a1 = *(const float4*)(xp + 4);
        xp += 32;
        bf16x8 af;
        af[0] = f2bf(a0.x); af[1] = f2bf(a0.y); af[2] = f2bf(a0.z); af[3] = f2bf(a0.w);
        af[4] = f2bf(a1.x); af[5] = f2bf(a1.y); af[6] = f2bf(a1.z); af[7] = f2bf(a1.w);
        #pragma unroll
        for (int f = 0; f < 12; ++f) {
            bf16x8 bf = *(const bf16x8*)(wp + (size_t)f * 512);
            acc[f] = __builtin_amdgcn_mfma_f32_16x16x32_bf16(af, bf, acc[f], 0, 0, 0);
        }
        wp += 12 * 512;
    }

    if (kh == 1) {
        #pragma unroll
        for (int f = 0; f < 12; ++f)
            *(f32x4*)&part[wm][f][l][0] = acc[f];
    }
    __syncthreads();
    if (kh == 0) {
        #pragma unroll
        for (int f = 0; f < 12; ++f)
            acc[f] += *(const f32x4*)&part[wm][f][l][0];
        #pragma unroll
        for (int f = 0; f < 12; ++f) {
            const int m = f >> 2;
            const int h = ((f & 3) << 4) + l15;
            if (m == 2) {
                // Vt[b][h][t], pack 4 consecutive t into one 8B store
                const long row = row0 + g * 4;
                const long bb = row >> 11;
                const int  t0 = (int)(row & 2047);
                short4v pkt;
                #pragma unroll
                for (int r = 0; r < 4; ++r) pkt[r] = f2bf(acc[f][r]);
                *(short4v*)&vt[(bb * 64 + h) * TT + t0] = pkt;
            } else {
                short* base = (m == 0) ? q : k;
                // fold 1/sqrt(H) AND log2(e) into q -> softmax uses exp2
                const float sc = (m == 0) ? (0.125f * 1.44269504f) : 1.0f;
                #pragma unroll
                for (int r = 0; r < 4; ++r) {
                    const long row = row0 + g * 4 + r;
                    base[row * 64 + h] = f2bf(acc[f][r] * sc);
                }
            }
        }
    }
}

// -------- XCD-pinned, load-balanced, pipelined MFMA flash attention --------
// Flat grid 512 blocks x 512 thr. batch = blockIdx&7 (pins batch <-> XCD so
// K/V/Q stay in that XCD's L2). Block = q-tile pair (p, 127-p): 33-34 kv
// chunks total; 8 waves split W_A:W_B proportional to each tile's chunk
// count -> every wave gets 4-5 chunks. Per-wave flash state; one barrier;
// variable-width (m,l,O) merge.
__global__ __launch_bounds__(512, 4)
void attn_v5(const short* __restrict__ qg,
             const short* __restrict__ kg,
             const short* __restrict__ vtg,
             float* __restrict__ out)
{
    __shared__ short Ps[8][16 * 64];     // per-wave P round-trip, swizzled
    __shared__ float Op[8][16][68];      // per-wave O partials
    __shared__ float Ml[8][16][2];       // per-wave (m, l)

    const int t   = threadIdx.x;
    const int L   = t & 63;
    const int w   = t >> 6;              // 0..7
    const int bid = blockIdx.x;
    const int b   = bid & 7;             // XCD pin: one batch per XCD
    const int p   = bid >> 3;            // pair id 0..63
    const int l15 = L & 15, g = L >> 4;

    const int stA = p, stB = 127 - p;
    const int nA  = stA / 4 + 1, nB = stB / 4 + 1;   // chunks per tile
    const int S   = nA + nB;                          // 33 or 34
    int WA = (8 * nA + (S >> 1)) / S;                 // waves for tile A
    WA = WA < 1 ? 1 : (WA > 7 ? 7 : WA);
    const int WB = 8 - WA;

    const bool isB   = (w >= WA);
    const int  q0    = (isB ? stB : stA) * 16;
    const int  nkv   = isB ? nB : nA;
    const int  strd  = isB ? WB : WA;
    const int  c0    = isB ? (w - WA) : w;

    bf16x8 qf[2];
    {
        const short* qp = qg + ((long)b * TT + q0 + l15) * 64 + g * 8;
        qf[0] = *(const bf16x8*)(qp);
        qf[1] = *(const bf16x8*)(qp + 32);
    }

    const f32x4 zero4 = {0.f, 0.f, 0.f, 0.f};
    f32x4 o[4] = {zero4, zero4, zero4, zero4};
    float mrun[4], lrun[4];
    #pragma unroll
    for (int r = 0; r < 4; ++r) { mrun[r] = -1e30f; lrun[r] = 0.f; }

    const short* kbase  = kg  + (long)b * TT * 64;
    const short* vtbase = vtg + (long)b * 64 * TT;

    {
        bf16x8 kf[8], vf[8];
        int c = c0;

        // prologue: K(first) + QK(first)
        #pragma unroll
        for (int cc = 0; cc < 4; ++cc)
            #pragma unroll
            for (int kc = 0; kc < 2; ++kc)
                kf[cc * 2 + kc] = *(const bf16x8*)(kbase + (long)(c * 64 + cc * 16 + l15) * 64 + kc * 32 + g * 8);
        f32x4 s[4];
        #pragma unroll
        for (int cc = 0; cc < 4; ++cc) s[cc] = zero4;
        __builtin_amdgcn_s_setprio(1);
        #pragma unroll
        for (int cc = 0; cc < 4; ++cc)
            #pragma unroll
            for (int kc = 0; kc < 2; ++kc)
                s[cc] = __builtin_amdgcn_mfma_f32_16x16x32_bf16(qf[kc], kf[cc * 2 + kc], s[cc], 0, 0, 0);
        __builtin_amdgcn_s_setprio(0);

        int cs = c;                  // chunk currently held in s
        c += strd;
        bool hasnext = (c < nkv);
        if (hasnext) {
            #pragma unroll
            for (int cc = 0; cc < 4; ++cc)
                #pragma unroll
                for (int kc = 0; kc < 2; ++kc)
                    kf[cc * 2 + kc] = *(const bf16x8*)(kbase + (long)(c * 64 + cc * 16 + l15) * 64 + kc * 32 + g * 8);
        }

        while (true) {
            const int kvs = cs * 64;
            // ---- issue V(cur) loads early ----
            #pragma unroll
            for (int nf = 0; nf < 4; ++nf)
                #pragma unroll
                for (int kc = 0; kc < 2; ++kc)
                    vf[nf * 2 + kc] = *(const bf16x8*)(vtbase + (long)(nf * 16 + l15) * TT + kvs + kc * 32 + g * 8);

            // ---- causal mask (diagonal chunks only) ----
            if (kvs + 63 > q0) {
                #pragma unroll
                for (int cc = 0; cc < 4; ++cc) {
                    const int kvg = kvs + cc * 16 + l15;
                    #pragma unroll
                    for (int r = 0; r < 4; ++r)
                        if (kvg > q0 + g * 4 + r) s[cc][r] = -1e30f;
                }
            }
            // ---- row max ----
            float mloc[4];
            #pragma unroll
            for (int r = 0; r < 4; ++r) {
                float m = fmaxf(fmaxf(s[0][r], s[1][r]), fmaxf(s[2][r], s[3][r]));
                m = fmaxf(m, __shfl_xor(m, 1));
                m = fmaxf(m, __shfl_xor(m, 2));
                m = fmaxf(m, __shfl_xor(m, 4));
                m = fmaxf(m, __shfl_xor(m, 8));
                mloc[r] = m;
            }
            // ---- defer-max rescale ----
            bool ok = (mloc[0] <= mrun[0] + 8.f) && (mloc[1] <= mrun[1] + 8.f) &&
                      (mloc[2] <= mrun[2] + 8.f) && (mloc[3] <= mrun[3] + 8.f);
            if (!__all(ok)) {
                #pragma unroll
                for (int r = 0; r < 4; ++r) {
                    const float mnew = fmaxf(mrun[r], mloc[r]);
                    const float a = exp2f(mrun[r] - mnew);
                    mrun[r] = mnew;
                    lrun[r] *= a;
                    #pragma unroll
                    for (int nf = 0; nf < 4; ++nf) o[nf][r] *= a;
                }
            }
            // ---- p = exp2(s-m), Ps write, lsum ----
            float lsum[4] = {0.f, 0.f, 0.f, 0.f};
            #pragma unroll
            for (int cc = 0; cc < 4; ++cc)
                #pragma unroll
                for (int r = 0; r < 4; ++r) {
                    float pv = exp2f(s[cc][r] - mrun[r]);
                    lsum[r] += pv;
                    const int ql = g * 4 + r, kvl = cc * 16 + l15;
                    Ps[w][(ql * 64 + kvl) ^ ((ql & 7) << 3)] = f2bf(pv);
                }
            #pragma unroll
            for (int r = 0; r < 4; ++r) {
                lsum[r] += __shfl_xor(lsum[r], 1);
                lsum[r] += __shfl_xor(lsum[r], 2);
                lsum[r] += __shfl_xor(lsum[r], 4);
                lsum[r] += __shfl_xor(lsum[r], 8);
                lrun[r] += lsum[r];
            }
            // ---- QK for NEXT chunk ----
            if (hasnext) {
                #pragma unroll
                for (int cc = 0; cc < 4; ++cc) s[cc] = zero4;
                __builtin_amdgcn_s_setprio(1);
                #pragma unroll
                for (int cc = 0; cc < 4; ++cc)
                    #pragma unroll
                    for (int kc = 0; kc < 2; ++kc)
                        s[cc] = __builtin_amdgcn_mfma_f32_16x16x32_bf16(qf[kc], kf[cc * 2 + kc], s[cc], 0, 0, 0);
                __builtin_amdgcn_s_setprio(0);
            }
            // ---- PV for CURRENT chunk ----
            __builtin_amdgcn_s_setprio(1);
            #pragma unroll
            for (int kc = 0; kc < 2; ++kc) {
                bf16x8 pa = *(const bf16x8*)&Ps[w][(l15 * 64 + kc * 32 + g * 8) ^ ((l15 & 7) << 3)];
                #pragma unroll
                for (int nf = 0; nf < 4; ++nf)
                    o[nf] = __builtin_amdgcn_mfma_f32_16x16x32_bf16(pa, vf[nf * 2 + kc], o[nf], 0, 0, 0);
            }
            __builtin_amdgcn_s_setprio(0);

            if (!hasnext) break;
            cs = c;
            c += strd;
            hasnext = (c < nkv);
            if (hasnext) {
                #pragma unroll
                for (int cc = 0; cc < 4; ++cc)
                    #pragma unroll
                    for (int kc = 0; kc < 2; ++kc)
                        kf[cc * 2 + kc] = *(const bf16x8*)(kbase + (long)(c * 64 + cc * 16 + l15) * 64 + kc * 32 + g * 8);
            }
        }
    }

    // ---- publish partials, single barrier, variable-width merge ----
    #pragma unroll
    for (int nf = 0; nf < 4; ++nf)
        #pragma unroll
        for (int r = 0; r < 4; ++r)
            Op[w][g * 4 + r][nf * 16 + l15] = o[nf][r];
    if (l15 == 0) {
        #pragma unroll
        for (int r = 0; r < 4; ++r) {
            Ml[w][g * 4 + r][0] = mrun[r];
            Ml[w][g * 4 + r][1] = lrun[r];
        }
    }
    __syncthreads();

    // waves 0-3 merge tile A rows, waves 4-7 merge tile B rows
    {
        const bool tb   = (w >= 4);
        const int  base = tb ? WA : 0;
        const int  cnt  = tb ? WB : WA;
        const int  oq0  = (tb ? stB : stA) * 16;
        #pragma unroll
        for (int rr = 0; rr < 4; ++rr) {
            const int row = (w & 3) * 4 + rr;
            float M = -1e30f;
            for (int j = 0; j < cnt; ++j)
                M = fmaxf(M, Ml[base + j][row][0]);
            float Ls = 0.f, val = 0.f;
            for (int j = 0; j < cnt; ++j) {
                const float a = exp2f(Ml[base + j][row][0] - M);
                Ls  += a * Ml[base + j][row][1];
                val += a * Op[base + j][row][L];
            }
            out[((long)b * TT + oq0 + row) * 64 + L] = val / Ls;
        }
    }
}

extern "C" void kernel_launch(void* const* d_in, const int* in_sizes, int n_in,
                              void* d_out, int out_size, void* d_ws, size_t ws_size,
                              hipStream_t stream)
{
    const float* x  = (const float*)d_in[0];
    const float* Wq = (const float*)d_in[1];
    const float* Wk = (const float*)d_in[2];
    const float* Wv = (const float*)d_in[3];
    float* out = (float*)d_out;

    const size_t n = (size_t)BB * TT * H;   // 1,048,576 per tensor
    short* q  = (short*)d_ws;
    short* k  = q + n;
    short* vt = k + n;                      // V transposed: [B][H][T]
    short* Wb = vt + n;                     // 196,608 shorts

    pack_w   <<<dim3(96),   256, 0, stream>>>(Wq, Wk, Wv, Wb);
    proj_mfma<<<dim3(512),  256, 0, stream>>>(x, Wb, q, k, vt);
    attn_v5  <<<dim3(512),  512, 0, stream>>>(q, k, vt, out);
}

// Round 7
// 73.321 us; speedup vs baseline: 1.3506x; 1.3506x over previous
//
#include <hip/hip_runtime.h>

#define E  1024
#define H  64
#define BB 8
#define TT 2048

typedef __attribute__((ext_vector_type(8))) short bf16x8;
typedef __attribute__((ext_vector_type(4))) float f32x4;
typedef __attribute__((ext_vector_type(8))) short short8;
typedef __attribute__((ext_vector_type(4))) short short4v;

__device__ __forceinline__ short f2bf(float f) {
    union { float f; unsigned u; } v; v.f = f;
    unsigned r = v.u + 0x7FFFu + ((v.u >> 16) & 1u);   // RNE
    return (short)(r >> 16);
}

// ---- pack W into B-fragment layout for mfma_f32_16x16x32_bf16 ----
__global__ __launch_bounds__(256)
void pack_w(const float* __restrict__ Wq, const float* __restrict__ Wk,
            const float* __restrict__ Wv, short* __restrict__ Wb)
{
    const int t  = blockIdx.x * 256 + threadIdx.x;   // 24576 total
    const int l  = t & 63;
    const int f  = (t >> 6) % 12;
    const int kc = t / 768;                          // kchunk 0..31
    const float* W = (f < 4) ? Wq : ((f < 8) ? Wk : Wv);
    const int e0 = kc * 32 + ((l >> 4) << 3);
    const int n  = ((f & 3) << 4) + (l & 15);
    short8 o;
    #pragma unroll
    for (int j = 0; j < 8; ++j) o[j] = f2bf(W[(e0 + j) * 64 + n]);
    *(short8*)&Wb[(size_t)t * 8] = o;
}

// ---- split-K MFMA projection; writes q,k row-major and V TRANSPOSED ----
__global__ __launch_bounds__(256)
void proj_mfma(const float* __restrict__ x, const short* __restrict__ Wb,
               short* __restrict__ q, short* __restrict__ k, short* __restrict__ vt)
{
    __shared__ float part[2][12][64][4];   // 24 KB: kh=1 partials
    const int t   = threadIdx.x;
    const int l   = t & 63;
    const int wid = t >> 6;
    const int wm  = wid & 1, kh = wid >> 1;
    const long row0 = (long)blockIdx.x * 32 + wm * 16;
    const int l15 = l & 15, g = l >> 4;

    f32x4 acc[12];
    #pragma unroll
    for (int f = 0; f < 12; ++f) acc[f] = (f32x4){0.f, 0.f, 0.f, 0.f};

    const float* xp = x + (row0 + l15) * E + kh * 512 + g * 8;
    const short* wp = Wb + (size_t)(kh * 16) * 12 * 512 + (size_t)l * 8;

    for (int kc = 0; kc < 16; ++kc) {
        float4 a0 = *(const float4*)(xp);
        float4 a1 = *(const float4*)(xp + 4);
        xp += 32;
        bf16x8 af;
        af[0] = f2bf(a0.x); af[1] = f2bf(a0.y); af[2] = f2bf(a0.z); af[3] = f2bf(a0.w);
        af[4] = f2bf(a1.x); af[5] = f2bf(a1.y); af[6] = f2bf(a1.z); af[7] = f2bf(a1.w);
        #pragma unroll
        for (int f = 0; f < 12; ++f) {
            bf16x8 bf = *(const bf16x8*)(wp + (size_t)f * 512);
            acc[f] = __builtin_amdgcn_mfma_f32_16x16x32_bf16(af, bf, acc[f], 0, 0, 0);
        }
        wp += 12 * 512;
    }

    if (kh == 1) {
        #pragma unroll
        for (int f = 0; f < 12; ++f)
            *(f32x4*)&part[wm][f][l][0] = acc[f];
    }
    __syncthreads();
    if (kh == 0) {
        #pragma unroll
        for (int f = 0; f < 12; ++f)
            acc[f] += *(const f32x4*)&part[wm][f][l][0];
        #pragma unroll
        for (int f = 0; f < 12; ++f) {
            const int m = f >> 2;
            const int h = ((f & 3) << 4) + l15;
            if (m == 2) {
                // Vt[b][h][t], pack 4 consecutive t into one 8B store
                const long row = row0 + g * 4;
                const long bb = row >> 11;
                const int  t0 = (int)(row & 2047);
                short4v pkt;
                #pragma unroll
                for (int r = 0; r < 4; ++r) pkt[r] = f2bf(acc[f][r]);
                *(short4v*)&vt[(bb * 64 + h) * TT + t0] = pkt;
            } else {
                short* base = (m == 0) ? q : k;
                // fold 1/sqrt(H) AND log2(e) into q -> softmax uses exp2
                const float sc = (m == 0) ? (0.125f * 1.44269504f) : 1.0f;
                #pragma unroll
                for (int r = 0; r < 4; ++r) {
                    const long row = row0 + g * 4 + r;
                    base[row * 64 + h] = f2bf(acc[f][r] * sc);
                }
            }
        }
    }
}

// -------- Barrier-free pipelined MFMA flash attention, XCD-pinned --------
// Flat grid 1024: b = blockIdx&7 -> with round-robin block->XCD dispatch,
// each XCD sees ONE batch (768 KB q/k/vt working set, L2-resident).
// st = 127 - (blockIdx>>3) keeps LPT. Inner loop identical to v4.
__global__ __launch_bounds__(256)
void attn_v6(const short* __restrict__ qg,
             const short* __restrict__ kg,
             const short* __restrict__ vtg,
             float* __restrict__ out)
{
    __shared__ short Ps[4][16 * 64];     // per-wave P round-trip, swizzled
    __shared__ float Op[4][16][68];      // per-wave O partials
    __shared__ float Ml[4][16][2];       // per-wave (m, l)

    const int t   = threadIdx.x;
    const int L   = t & 63;
    const int w   = t >> 6;
    const int bid = blockIdx.x;
    const int b   = bid & 7;             // XCD pin: one batch per XCD
    const int st  = 127 - (bid >> 3);    // LPT: heavy tiles first
    const int q0  = st * 16;
    const int qhi = q0 + 15;
    const int l15 = L & 15, g = L >> 4;

    bf16x8 qf[2];
    {
        const short* qp = qg + ((long)b * TT + q0 + l15) * 64 + g * 8;
        qf[0] = *(const bf16x8*)(qp);
        qf[1] = *(const bf16x8*)(qp + 32);
    }

    const f32x4 zero4 = {0.f, 0.f, 0.f, 0.f};
    f32x4 o[4] = {zero4, zero4, zero4, zero4};
    float mrun[4], lrun[4];
    #pragma unroll
    for (int r = 0; r < 4; ++r) { mrun[r] = -1e30f; lrun[r] = 0.f; }

    const short* kbase  = kg  + (long)b * TT * 64;
    const short* vtbase = vtg + (long)b * 64 * TT;

    int kv = w * 64;
    if (kv <= qhi) {
        bf16x8 kf[8], vf[8];

        // prologue: K(first) + QK(first)
        #pragma unroll
        for (int c = 0; c < 4; ++c)
            #pragma unroll
            for (int kc = 0; kc < 2; ++kc)
                kf[c * 2 + kc] = *(const bf16x8*)(kbase + (long)(kv + c * 16 + l15) * 64 + kc * 32 + g * 8);
        f32x4 s[4];
        #pragma unroll
        for (int c = 0; c < 4; ++c) s[c] = zero4;
        __builtin_amdgcn_s_setprio(1);
        #pragma unroll
        for (int c = 0; c < 4; ++c)
            #pragma unroll
            for (int kc = 0; kc < 2; ++kc)
                s[c] = __builtin_amdgcn_mfma_f32_16x16x32_bf16(qf[kc], kf[c * 2 + kc], s[c], 0, 0, 0);
        __builtin_amdgcn_s_setprio(0);

        int kvs = kv;            // chunk id currently held in s
        kv += 256;
        bool hasnext = (kv <= qhi);
        if (hasnext) {
            #pragma unroll
            for (int c = 0; c < 4; ++c)
                #pragma unroll
                for (int kc = 0; kc < 2; ++kc)
                    kf[c * 2 + kc] = *(const bf16x8*)(kbase + (long)(kv + c * 16 + l15) * 64 + kc * 32 + g * 8);
        }

        while (true) {
            // ---- issue V(cur) loads early (used at the end of this iter) ----
            #pragma unroll
            for (int nf = 0; nf < 4; ++nf)
                #pragma unroll
                for (int kc = 0; kc < 2; ++kc)
                    vf[nf * 2 + kc] = *(const bf16x8*)(vtbase + (long)(nf * 16 + l15) * TT + kvs + kc * 32 + g * 8);

            // ---- causal mask (diagonal chunks only) ----
            if (kvs + 63 > q0) {
                #pragma unroll
                for (int c = 0; c < 4; ++c) {
                    const int kvg = kvs + c * 16 + l15;
                    #pragma unroll
                    for (int r = 0; r < 4; ++r)
                        if (kvg > q0 + g * 4 + r) s[c][r] = -1e30f;
                }
            }
            // ---- row max ----
            float mloc[4];
            #pragma unroll
            for (int r = 0; r < 4; ++r) {
                float m = fmaxf(fmaxf(s[0][r], s[1][r]), fmaxf(s[2][r], s[3][r]));
                m = fmaxf(m, __shfl_xor(m, 1));
                m = fmaxf(m, __shfl_xor(m, 2));
                m = fmaxf(m, __shfl_xor(m, 4));
                m = fmaxf(m, __shfl_xor(m, 8));
                mloc[r] = m;
            }
            // ---- defer-max: rescale only when the max really grows ----
            bool ok = (mloc[0] <= mrun[0] + 8.f) && (mloc[1] <= mrun[1] + 8.f) &&
                      (mloc[2] <= mrun[2] + 8.f) && (mloc[3] <= mrun[3] + 8.f);
            if (!__all(ok)) {
                #pragma unroll
                for (int r = 0; r < 4; ++r) {
                    const float mnew = fmaxf(mrun[r], mloc[r]);
                    const float a = exp2f(mrun[r] - mnew);
                    mrun[r] = mnew;
                    lrun[r] *= a;
                    #pragma unroll
                    for (int nf = 0; nf < 4; ++nf) o[nf][r] *= a;
                }
            }
            // ---- p = exp2(s-m), Ps write, lsum ----
            float lsum[4] = {0.f, 0.f, 0.f, 0.f};
            #pragma unroll
            for (int c = 0; c < 4; ++c)
                #pragma unroll
                for (int r = 0; r < 4; ++r) {
                    float p = exp2f(s[c][r] - mrun[r]);
                    lsum[r] += p;
                    const int ql = g * 4 + r, kvl = c * 16 + l15;
                    Ps[w][(ql * 64 + kvl) ^ ((ql & 7) << 3)] = f2bf(p);
                }
            #pragma unroll
            for (int r = 0; r < 4; ++r) {
                lsum[r] += __shfl_xor(lsum[r], 1);
                lsum[r] += __shfl_xor(lsum[r], 2);
                lsum[r] += __shfl_xor(lsum[r], 4);
                lsum[r] += __shfl_xor(lsum[r], 8);
                lrun[r] += lsum[r];
            }
            // ---- QK for NEXT chunk (covers Ps write->read + V latency) ----
            if (hasnext) {
                #pragma unroll
                for (int c = 0; c < 4; ++c) s[c] = zero4;
                __builtin_amdgcn_s_setprio(1);
                #pragma unroll
                for (int c = 0; c < 4; ++c)
                    #pragma unroll
                    for (int kc = 0; kc < 2; ++kc)
                        s[c] = __builtin_amdgcn_mfma_f32_16x16x32_bf16(qf[kc], kf[c * 2 + kc], s[c], 0, 0, 0);
                __builtin_amdgcn_s_setprio(0);
            }
            // ---- PV for CURRENT chunk ----
            __builtin_amdgcn_s_setprio(1);
            #pragma unroll
            for (int kc = 0; kc < 2; ++kc) {
                bf16x8 pa = *(const bf16x8*)&Ps[w][(l15 * 64 + kc * 32 + g * 8) ^ ((l15 & 7) << 3)];
                #pragma unroll
                for (int nf = 0; nf < 4; ++nf)
                    o[nf] = __builtin_amdgcn_mfma_f32_16x16x32_bf16(pa, vf[nf * 2 + kc], o[nf], 0, 0, 0);
            }
            __builtin_amdgcn_s_setprio(0);

            if (!hasnext) break;
            kvs = kv;
            kv += 256;
            hasnext = (kv <= qhi);
            if (hasnext) {
                #pragma unroll
                for (int c = 0; c < 4; ++c)
                    #pragma unroll
                    for (int kc = 0; kc < 2; ++kc)
                        kf[c * 2 + kc] = *(const bf16x8*)(kbase + (long)(kv + c * 16 + l15) * 64 + kc * 32 + g * 8);
            }
        }
    }

    // ---- publish partials, single barrier, 4-way merge ----
    #pragma unroll
    for (int nf = 0; nf < 4; ++nf)
        #pragma unroll
        for (int r = 0; r < 4; ++r)
            Op[w][g * 4 + r][nf * 16 + l15] = o[nf][r];
    if (l15 == 0) {
        #pragma unroll
        for (int r = 0; r < 4; ++r) {
            Ml[w][g * 4 + r][0] = mrun[r];
            Ml[w][g * 4 + r][1] = lrun[r];
        }
    }
    __syncthreads();

    #pragma unroll
    for (int rr = 0; rr < 4; ++rr) {
        const int row = w * 4 + rr;
        float m0 = Ml[0][row][0], m1 = Ml[1][row][0];
        float m2 = Ml[2][row][0], m3 = Ml[3][row][0];
        float M = fmaxf(fmaxf(m0, m1), fmaxf(m2, m3));
        float a0 = exp2f(m0 - M), a1 = exp2f(m1 - M);
        float a2 = exp2f(m2 - M), a3 = exp2f(m3 - M);
        float Ls = a0 * Ml[0][row][1] + a1 * Ml[1][row][1] +
                   a2 * Ml[2][row][1] + a3 * Ml[3][row][1];
        float val = a0 * Op[0][row][L] + a1 * Op[1][row][L] +
                    a2 * Op[2][row][L] + a3 * Op[3][row][L];
        out[((long)b * TT + q0 + row) * 64 + L] = val / Ls;
    }
}

extern "C" void kernel_launch(void* const* d_in, const int* in_sizes, int n_in,
                              void* d_out, int out_size, void* d_ws, size_t ws_size,
                              hipStream_t stream)
{
    const float* x  = (const float*)d_in[0];
    const float* Wq = (const float*)d_in[1];
    const float* Wk = (const float*)d_in[2];
    const float* Wv = (const float*)d_in[3];
    float* out = (float*)d_out;

    const size_t n = (size_t)BB * TT * H;   // 1,048,576 per tensor
    short* q  = (short*)d_ws;
    short* k  = q + n;
    short* vt = k + n;                      // V transposed: [B][H][T]
    short* Wb = vt + n;                     // 196,608 shorts

    pack_w   <<<dim3(96),   256, 0, stream>>>(Wq, Wk, Wv, Wb);
    proj_mfma<<<dim3(512),  256, 0, stream>>>(x, Wb, q, k, vt);
    attn_v6  <<<dim3(1024), 256, 0, stream>>>(q, k, vt, out);
}

// Round 9
// 61.060 us; speedup vs baseline: 1.6218x; 1.2008x over previous
//
#include <hip/hip_runtime.h>

#define E  1024
#define H  64
#define BB 8
#define TT 2048

typedef __attribute__((ext_vector_type(8)))  short bf16x8;
typedef __attribute__((ext_vector_type(4)))  float f32x4;
typedef __attribute__((ext_vector_type(16))) float f32x16;
typedef __attribute__((ext_vector_type(8)))  short short8;
typedef __attribute__((ext_vector_type(4)))  short short4v;
typedef __attribute__((ext_vector_type(4)))  unsigned u32x4;

__device__ __forceinline__ short f2bf(float f) {
    union { float f; unsigned u; } v; v.f = f;
    unsigned r = v.u + 0x7FFFu + ((v.u >> 16) & 1u);   // RNE
    return (short)(r >> 16);
}

// fast 2^x via the HW transcendental (no HIP __exp2f intrinsic exists)
__device__ __forceinline__ float fexp2(float x) {
    float r;
    asm("v_exp_f32 %0, %1" : "=v"(r) : "v"(x));
    return r;
}

// ---- pack W into B-fragment layout for mfma_f32_16x16x32_bf16 ----
__global__ __launch_bounds__(256)
void pack_w(const float* __restrict__ Wq, const float* __restrict__ Wk,
            const float* __restrict__ Wv, short* __restrict__ Wb)
{
    const int t  = blockIdx.x * 256 + threadIdx.x;   // 24576 total
    const int l  = t & 63;
    const int f  = (t >> 6) % 12;
    const int kc = t / 768;                          // kchunk 0..31
    const float* W = (f < 4) ? Wq : ((f < 8) ? Wk : Wv);
    const int e0 = kc * 32 + ((l >> 4) << 3);
    const int n  = ((f & 3) << 4) + (l & 15);
    short8 o;
    #pragma unroll
    for (int j = 0; j < 8; ++j) o[j] = f2bf(W[(e0 + j) * 64 + n]);
    *(short8*)&Wb[(size_t)t * 8] = o;
}

// ---- split-K MFMA projection; writes q,k row-major and V TRANSPOSED ----
__global__ __launch_bounds__(256)
void proj_mfma(const float* __restrict__ x, const short* __restrict__ Wb,
               short* __restrict__ q, short* __restrict__ k, short* __restrict__ vt)
{
    __shared__ float part[2][12][64][4];   // 24 KB: kh=1 partials
    const int t   = threadIdx.x;
    const int l   = t & 63;
    const int wid = t >> 6;
    const int wm  = wid & 1, kh = wid >> 1;
    const long row0 = (long)blockIdx.x * 32 + wm * 16;
    const int l15 = l & 15, g = l >> 4;

    f32x4 acc[12];
    #pragma unroll
    for (int f = 0; f < 12; ++f) acc[f] = (f32x4){0.f, 0.f, 0.f, 0.f};

    const float* xp = x + (row0 + l15) * E + kh * 512 + g * 8;
    const short* wp = Wb + (size_t)(kh * 16) * 12 * 512 + (size_t)l * 8;

    for (int kc = 0; kc < 16; ++kc) {
        float4 a0 = *(const float4*)(xp);
        float4 a1 = *(const float4*)(xp + 4);
        xp += 32;
        bf16x8 af;
        af[0] = f2bf(a0.x); af[1] = f2bf(a0.y); af[2] = f2bf(a0.z); af[3] = f2bf(a0.w);
        af[4] = f2bf(a1.x); af[5] = f2bf(a1.y); af[6] = f2bf(a1.z); af[7] = f2bf(a1.w);
        #pragma unroll
        for (int f = 0; f < 12; ++f) {
            bf16x8 bf = *(const bf16x8*)(wp + (size_t)f * 512);
            acc[f] = __builtin_amdgcn_mfma_f32_16x16x32_bf16(af, bf, acc[f], 0, 0, 0);
        }
        wp += 12 * 512;
    }

    if (kh == 1) {
        #pragma unroll
        for (int f = 0; f < 12; ++f)
            *(f32x4*)&part[wm][f][l][0] = acc[f];
    }
    __syncthreads();
    if (kh == 0) {
        #pragma unroll
        for (int f = 0; f < 12; ++f)
            acc[f] += *(const f32x4*)&part[wm][f][l][0];
        #pragma unroll
        for (int f = 0; f < 12; ++f) {
            const int m = f >> 2;
            const int h = ((f & 3) << 4) + l15;
            if (m == 2) {
                // Vt[b][h][t], pack 4 consecutive t into one 8B store
                const long row = row0 + g * 4;
                const long bb = row >> 11;
                const int  t0 = (int)(row & 2047);
                short4v pkt;
                #pragma unroll
                for (int r = 0; r < 4; ++r) pkt[r] = f2bf(acc[f][r]);
                *(short4v*)&vt[(bb * 64 + h) * TT + t0] = pkt;
            } else {
                short* base = (m == 0) ? q : k;
                // fold 1/sqrt(H) AND log2(e) into q -> softmax uses exp2
                const float sc = (m == 0) ? (0.125f * 1.44269504f) : 1.0f;
                #pragma unroll
                for (int r = 0; r < 4; ++r) {
                    const long row = row0 + g * 4 + r;
                    base[row * 64 + h] = f2bf(acc[f][r] * sc);
                }
            }
        }
    }
}

// ---- 32x32 swapped-QK^T flash attention (T12: cvt_pk + permlane32_swap) ----
// Grid 256 = 32 tile-pairs x 8 batches (b = bid&7 -> XCD pin). Block = 512
// thr = 8 waves on tile pair (pr, 63-pr) = 65 chunks of 32 kv; waves split
// proportionally (8-10 chunks each). Swapped QK^T: lane owns q-row (L&31),
// P^T col in regs -> lane-local softmax, in-register P->bf16 B-frags.
__global__ __launch_bounds__(512)
void attn_v8(const short* __restrict__ qg,
             const short* __restrict__ kg,
             const short* __restrict__ vtg,
             float* __restrict__ out)
{
    __shared__ float Op[8][32][66];      // per-wave O^T partials [w][q][h]
    __shared__ float Ml[8][32][2];       // per-wave (m, l)

    const int t   = threadIdx.x;
    const int L   = t & 63;
    const int w   = t >> 6;
    const int bid = blockIdx.x;
    const int b   = bid & 7;             // XCD pin
    const int pr  = bid >> 3;            // pair 0..31
    const int l31 = L & 31, hi = L >> 5;

    const int stA = pr, stB = 63 - pr;
    const int nA = stA + 1;
    int WA = (8 * nA + 32) / 65;         // round(8*nA/65)
    WA = WA < 1 ? 1 : (WA > 7 ? 7 : WA);
    const int WB = 8 - WA;

    const bool isB  = (w >= WA);
    const int  st   = isB ? stB : stA;
    const int  q0   = st * 32;
    const int  strd = isB ? WB : WA;
    const int  c0   = isB ? (w - WA) : w;

    // Q B-frags: col=q=l31, k=e=es*16+hi*8+j
    bf16x8 qf[4];
    {
        const short* qp = qg + ((long)b * TT + q0 + l31) * 64 + hi * 8;
        qf[0] = *(const bf16x8*)(qp);
        qf[1] = *(const bf16x8*)(qp + 16);
        qf[2] = *(const bf16x8*)(qp + 32);
        qf[3] = *(const bf16x8*)(qp + 48);
    }

    f32x16 o0 = {}, o1 = {};
    float mrun = -1e30f, lrun = 0.f;

    const short* kbase = kg  + ((long)b * TT + l31) * 64 + hi * 8;
    const short* vbase = vtg + ((long)b * 64 + l31) * TT + hi * 8;

    for (int ci = c0; ci <= st; ci += strd) {
        const int kvs = ci * 32;
        // K A-frags: row=kv=kvs+l31, k=e (contiguous 16B)
        const short* kp = kbase + (long)kvs * 64;
        bf16x8 kf0 = *(const bf16x8*)(kp);
        bf16x8 kf1 = *(const bf16x8*)(kp + 16);
        bf16x8 kf2 = *(const bf16x8*)(kp + 32);
        bf16x8 kf3 = *(const bf16x8*)(kp + 48);
        // V A-frags issued early: row=h=nf*32+l31, k=kv slice
        const short* vp = vbase + kvs;
        bf16x8 vf00 = *(const bf16x8*)(vp);
        bf16x8 vf01 = *(const bf16x8*)(vp + 16);
        bf16x8 vf10 = *(const bf16x8*)(vp + 32 * TT);
        bf16x8 vf11 = *(const bf16x8*)(vp + 32 * TT + 16);

        // ---- QK^T swapped: S^T[kv,q]; D: col=q=l31, row=crow(r,hi) ----
        f32x16 s = {};
        __builtin_amdgcn_s_setprio(1);
        s = __builtin_amdgcn_mfma_f32_32x32x16_bf16(kf0, qf[0], s, 0, 0, 0);
        s = __builtin_amdgcn_mfma_f32_32x32x16_bf16(kf1, qf[1], s, 0, 0, 0);
        s = __builtin_amdgcn_mfma_f32_32x32x16_bf16(kf2, qf[2], s, 0, 0, 0);
        s = __builtin_amdgcn_mfma_f32_32x32x16_bf16(kf3, qf[3], s, 0, 0, 0);
        __builtin_amdgcn_s_setprio(0);

        // ---- causal mask: only the diagonal chunk ----
        if (kvs == q0) {
            #pragma unroll
            for (int r = 0; r < 16; ++r) {
                const int crow = (r & 3) + 8 * (r >> 2) + 4 * hi;
                if (crow > l31) s[r] = -1e30f;
            }
        }
        // ---- lane-local row max (q-row = l31) + hi-half exchange ----
        float m01 = fmaxf(s[0], s[1]),   m23 = fmaxf(s[2], s[3]);
        float m45 = fmaxf(s[4], s[5]),   m67 = fmaxf(s[6], s[7]);
        float m89 = fmaxf(s[8], s[9]),   mab = fmaxf(s[10], s[11]);
        float mcd = fmaxf(s[12], s[13]), mef = fmaxf(s[14], s[15]);
        float mloc = fmaxf(fmaxf(fmaxf(m01, m23), fmaxf(m45, m67)),
                           fmaxf(fmaxf(m89, mab), fmaxf(mcd, mef)));
        mloc = fmaxf(mloc, __shfl_xor(mloc, 32));
        // ---- defer-max rescale (THR = 8 in exp2 units) ----
        if (__any(mloc > mrun + 8.f)) {
            const float mnew = fmaxf(mrun, mloc);
            const float a = fexp2(mrun - mnew);
            mrun = mnew;
            lrun *= a;
            #pragma unroll
            for (int r = 0; r < 16; ++r) { o0[r] *= a; o1[r] *= a; }
        }
        // ---- p = exp2(s - m) in place; lane-local sum ----
        #pragma unroll
        for (int r = 0; r < 16; ++r) s[r] = fexp2(s[r] - mrun);
        {
            float s01 = (s[0] + s[1]) + (s[2] + s[3]);
            float s23 = (s[4] + s[5]) + (s[6] + s[7]);
            float s45 = (s[8] + s[9]) + (s[10] + s[11]);
            float s67 = (s[12] + s[13]) + (s[14] + s[15]);
            float lsum = (s01 + s23) + (s45 + s67);
            lsum += __shfl_xor(lsum, 32);
            lrun += lsum;
        }
        // ---- in-register P->bf16 B-frags: 8 cvt_pk + 4 permlane32_swap ----
        unsigned wv[8];
        #pragma unroll
        for (int i = 0; i < 8; ++i)
            asm("v_cvt_pk_bf16_f32 %0, %1, %2" : "=v"(wv[i]) : "v"(s[2 * i]), "v"(s[2 * i + 1]));
        unsigned p00 = wv[0], p02 = wv[2];   // ks=0: words 0,2
        unsigned p01 = wv[1], p03 = wv[3];   // ks=0: words 1,3
        unsigned p10 = wv[4], p12 = wv[6];   // ks=1
        unsigned p11 = wv[5], p13 = wv[7];
        asm("v_permlane32_swap_b32 %0, %1" : "+v"(p00), "+v"(p02));
        asm("v_permlane32_swap_b32 %0, %1" : "+v"(p01), "+v"(p03));
        asm("v_permlane32_swap_b32 %0, %1" : "+v"(p10), "+v"(p12));
        asm("v_permlane32_swap_b32 %0, %1" : "+v"(p11), "+v"(p13));
        u32x4 pb0u = {p00, p01, p02, p03};
        u32x4 pb1u = {p10, p11, p12, p13};
        bf16x8 pb0, pb1;
        __builtin_memcpy(&pb0, &pb0u, 16);
        __builtin_memcpy(&pb1, &pb1u, 16);
        // ---- PV: O^T[h,q] += V^T x P^T ----
        __builtin_amdgcn_s_setprio(1);
        o0 = __builtin_amdgcn_mfma_f32_32x32x16_bf16(vf00, pb0, o0, 0, 0, 0);
        o0 = __builtin_amdgcn_mfma_f32_32x32x16_bf16(vf01, pb1, o0, 0, 0, 0);
        o1 = __builtin_amdgcn_mfma_f32_32x32x16_bf16(vf10, pb0, o1, 0, 0, 0);
        o1 = __builtin_amdgcn_mfma_f32_32x32x16_bf16(vf11, pb1, o1, 0, 0, 0);
        __builtin_amdgcn_s_setprio(0);
    }

    // ---- publish partials; single barrier; variable-width merge ----
    #pragma unroll
    for (int r = 0; r < 16; ++r) {
        const int h = (r & 3) + 8 * (r >> 2) + 4 * hi;
        Op[w][l31][h]      = o0[r];
        Op[w][l31][32 + h] = o1[r];
    }
    if (hi == 0) {
        Ml[w][l31][0] = mrun;
        Ml[w][l31][1] = lrun;
    }
    __syncthreads();

    // waves 0-3 merge tile A rows, 4-7 tile B rows; lane L = output col h
    {
        const bool tb   = (w >= 4);
        const int  base = tb ? WA : 0;
        const int  cnt  = tb ? WB : WA;
        const long oq0  = (long)(tb ? stB : stA) * 32;
        #pragma unroll
        for (int rr = 0; rr < 8; ++rr) {
            const int row = (w & 3) * 8 + rr;
            float M = -1e30f;
            for (int j = 0; j < cnt; ++j)
                M = fmaxf(M, Ml[base + j][row][0]);
            float Ls = 0.f, val = 0.f;
            for (int j = 0; j < cnt; ++j) {
                const float a = fexp2(Ml[base + j][row][0] - M);
                Ls  += a * Ml[base + j][row][1];
                val += a * Op[base + j][row][L];
            }
            out[((long)b * TT + oq0 + row) * 64 + L] = val / Ls;
        }
    }
}

extern "C" void kernel_launch(void* const* d_in, const int* in_sizes, int n_in,
                              void* d_out, int out_size, void* d_ws, size_t ws_size,
                              hipStream_t stream)
{
    const float* x  = (const float*)d_in[0];
    const float* Wq = (const float*)d_in[1];
    const float* Wk = (const float*)d_in[2];
    const float* Wv = (const float*)d_in[3];
    float* out = (float*)d_out;

    const size_t n = (size_t)BB * TT * H;   // 1,048,576 per tensor
    short* q  = (short*)d_ws;
    short* k  = q + n;
    short* vt = k + n;                      // V transposed: [B][H][T]
    short* Wb = vt + n;                     // 196,608 shorts

    pack_w   <<<dim3(96),  256, 0, stream>>>(Wq, Wk, Wv, Wb);
    proj_mfma<<<dim3(512), 256, 0, stream>>>(x, Wb, q, k, vt);
    attn_v8  <<<dim3(256), 512, 0, stream>>>(q, k, vt, out);
}